// Round 1
// baseline (2237.602 us; speedup 1.0000x reference)
//
#include <hip/hip_runtime.h>
#include <hip/hip_bf16.h>
#include <math.h>

#define B_ 16384
#define D_ 2048
#define H_ 2048
#define E_ 6
#define C_ 1024

typedef __attribute__((ext_vector_type(8))) short short8;
typedef __attribute__((ext_vector_type(4))) float f32x4;

__device__ __forceinline__ unsigned short f2bf(float f) {
    __hip_bfloat16 h = __float2bfloat16(f);
    return *reinterpret_cast<unsigned short*>(&h);
}

__device__ __forceinline__ void async_copy16(const unsigned short* g, unsigned short* l) {
    __builtin_amdgcn_global_load_lds(
        (const __attribute__((address_space(1))) unsigned int*)(g),
        (__attribute__((address_space(3))) unsigned int*)(l), 16, 0, 0);
}

// ---------------- gate: fp64 logits, top-3, softmax, routing lists ----------------
__global__ void gate_kernel(const float* __restrict__ x, const float* __restrict__ gW,
                            const float* __restrict__ gb, float* __restrict__ gw_out,
                            int* __restrict__ counts, int* __restrict__ rowlist,
                            float* __restrict__ wtslist) {
    int wave = threadIdx.x >> 6;
    int lane = threadIdx.x & 63;
    int row  = blockIdx.x * 4 + wave;
    const float* xr = x + (size_t)row * D_;
    double acc[E_] = {0, 0, 0, 0, 0, 0};
    for (int i = 0; i < D_ / 64; ++i) {
        int d = i * 64 + lane;
        double xv = (double)xr[d];
#pragma unroll
        for (int e = 0; e < E_; ++e) acc[e] += xv * (double)gW[e * D_ + d];
    }
#pragma unroll
    for (int off = 32; off > 0; off >>= 1) {
#pragma unroll
        for (int e = 0; e < E_; ++e) acc[e] += __shfl_down(acc[e], off);
    }
    if (lane == 0) {
        double lg[E_];
#pragma unroll
        for (int e = 0; e < E_; ++e) lg[e] = acc[e] + (double)gb[e];
        // top-3 selection (strict >, ties -> lowest index, matches lax.top_k)
        bool used[E_] = {false, false, false, false, false, false};
        int idx[3]; double val[3];
        for (int k = 0; k < 3; ++k) {
            int best = -1; double bv = -1e300;
            for (int e = 0; e < E_; ++e)
                if (!used[e] && lg[e] > bv) { bv = lg[e]; best = e; }
            used[best] = true; idx[k] = best; val[k] = bv;
        }
        double m = val[0];
        double w[3]; double s = 0.0;
        for (int k = 0; k < 3; ++k) { w[k] = exp(val[k] - m); s += w[k]; }
        float gwv[E_] = {0.f, 0.f, 0.f, 0.f, 0.f, 0.f};
        for (int k = 0; k < 3; ++k) gwv[idx[k]] = (float)(w[k] / s);
#pragma unroll
        for (int e = 0; e < E_; ++e) gw_out[(size_t)row * E_ + e] = gwv[e];
        for (int k = 0; k < 3; ++k) {
            int e = idx[k];
            int pos = atomicAdd(&counts[e], 1);
            rowlist[(size_t)e * B_ + pos] = row * 3 + k;   // global slot id
            wtslist[(size_t)e * B_ + pos] = (float)(w[k] / s);
        }
    }
}

// ---------------- f32 -> bf16 cast (vectorized) ----------------
__global__ void cast_f32_bf16(const float* __restrict__ in, unsigned short* __restrict__ out, int n4) {
    int i = blockIdx.x * blockDim.x + threadIdx.x;
    if (i < n4) {
        float4 v = ((const float4*)in)[i];
        ushort4 u;
        u.x = f2bf(v.x); u.y = f2bf(v.y); u.z = f2bf(v.z); u.w = f2bf(v.w);
        ((ushort4*)out)[i] = u;
    }
}

// ---------------- GEMM1: h[slot, n] = gelu(x[row] @ W1[e]^T + b1[e]) ----------------
__global__ __launch_bounds__(256) void gemm1_kernel(
    const unsigned short* __restrict__ xb, const unsigned short* __restrict__ W1b,
    const float* __restrict__ b1, const int* __restrict__ counts,
    const int* __restrict__ rowlist, unsigned short* __restrict__ hbuf) {
    int e = blockIdx.z;
    int cnt = counts[e];
    int m0 = blockIdx.y * 128;
    if (m0 >= cnt) return;
    int n0 = blockIdx.x * 128;

    __shared__ __align__(16) unsigned short At[128 * 64];
    __shared__ __align__(16) unsigned short Bt[128 * 64];
    __shared__ int rows_s[128];
    int tid = threadIdx.x;
    if (tid < 128) {
        int idx = m0 + tid;
        if (idx >= cnt) idx = cnt - 1;
        rows_s[tid] = rowlist[(size_t)e * B_ + idx];
    }
    __syncthreads();

    const unsigned short* aptr[4];
    const unsigned short* bptr[4];
#pragma unroll
    for (int it = 0; it < 4; ++it) {
        int seg = it * 256 + tid;
        int r = seg >> 3, c = seg & 7;
        aptr[it] = xb + (size_t)(rows_s[r] / 3) * D_ + c * 8;
        bptr[it] = W1b + (size_t)e * H_ * D_ + (size_t)(n0 + r) * D_ + c * 8;
    }
    int lane = tid & 63;
    int wv = tid >> 6;
    int wm = (wv & 1) * 64;
    int wn = (wv >> 1) * 64;
    int fm = lane & 15;
    int kg = lane >> 4;
    f32x4 acc[4][4] = {};

    for (int k0 = 0; k0 < D_; k0 += 64) {
#pragma unroll
        for (int it = 0; it < 4; ++it) {
            async_copy16(aptr[it] + k0, At + (it * 256 + tid) * 8);
            async_copy16(bptr[it] + k0, Bt + (it * 256 + tid) * 8);
        }
        __syncthreads();
#pragma unroll
        for (int kk = 0; kk < 2; ++kk) {
            short8 af[4], bfr[4];
#pragma unroll
            for (int mi = 0; mi < 4; ++mi)
                af[mi] = *(const short8*)(At + (wm + mi * 16 + fm) * 64 + kk * 32 + kg * 8);
#pragma unroll
            for (int ni = 0; ni < 4; ++ni)
                bfr[ni] = *(const short8*)(Bt + (wn + ni * 16 + fm) * 64 + kk * 32 + kg * 8);
#pragma unroll
            for (int mi = 0; mi < 4; ++mi)
#pragma unroll
                for (int ni = 0; ni < 4; ++ni)
                    acc[mi][ni] = __builtin_amdgcn_mfma_f32_16x16x32_bf16(af[mi], bfr[ni], acc[mi][ni], 0, 0, 0);
        }
        __syncthreads();
    }

    int rlim = cnt - m0;
#pragma unroll
    for (int mi = 0; mi < 4; ++mi) {
#pragma unroll
        for (int i = 0; i < 4; ++i) {
            int r = wm + mi * 16 + kg * 4 + i;
            if (r < rlim) {
                size_t base = (size_t)rows_s[r] * H_ + n0;
#pragma unroll
                for (int ni = 0; ni < 4; ++ni) {
                    int col = wn + ni * 16 + fm;
                    float v = acc[mi][ni][i] + b1[e * H_ + n0 + col];
                    v = 0.5f * v * (1.0f + erff(v * 0.70710678118654752f)); // exact GELU
                    hbuf[base + col] = f2bf(v);
                }
            }
        }
    }
}

// ---------------- GEMM2: out[row] += w * (h[slot] @ W2[e]^T + b2[e]) ----------------
__global__ __launch_bounds__(256) void gemm2_kernel(
    const unsigned short* __restrict__ hbuf, const unsigned short* __restrict__ W2b,
    const float* __restrict__ b2, const int* __restrict__ counts,
    const int* __restrict__ rowlist, const float* __restrict__ wtslist,
    float* __restrict__ out) {
    int e = blockIdx.z;
    int cnt = counts[e];
    int m0 = blockIdx.y * 128;
    if (m0 >= cnt) return;
    int n0 = blockIdx.x * 128;

    __shared__ __align__(16) unsigned short At[128 * 64];
    __shared__ __align__(16) unsigned short Bt[128 * 64];
    __shared__ int rows_s[128];
    __shared__ float wts_s[128];
    int tid = threadIdx.x;
    if (tid < 128) {
        int idx = m0 + tid;
        if (idx >= cnt) idx = cnt - 1;
        rows_s[tid] = rowlist[(size_t)e * B_ + idx];
        wts_s[tid] = wtslist[(size_t)e * B_ + idx];
    }
    __syncthreads();

    const unsigned short* aptr[4];
    const unsigned short* bptr[4];
#pragma unroll
    for (int it = 0; it < 4; ++it) {
        int seg = it * 256 + tid;
        int r = seg >> 3, c = seg & 7;
        aptr[it] = hbuf + (size_t)rows_s[r] * H_ + c * 8;
        bptr[it] = W2b + (size_t)e * C_ * H_ + (size_t)(n0 + r) * H_ + c * 8;
    }
    int lane = tid & 63;
    int wv = tid >> 6;
    int wm = (wv & 1) * 64;
    int wn = (wv >> 1) * 64;
    int fm = lane & 15;
    int kg = lane >> 4;
    f32x4 acc[4][4] = {};

    for (int k0 = 0; k0 < H_; k0 += 64) {
#pragma unroll
        for (int it = 0; it < 4; ++it) {
            async_copy16(aptr[it] + k0, At + (it * 256 + tid) * 8);
            async_copy16(bptr[it] + k0, Bt + (it * 256 + tid) * 8);
        }
        __syncthreads();
#pragma unroll
        for (int kk = 0; kk < 2; ++kk) {
            short8 af[4], bfr[4];
#pragma unroll
            for (int mi = 0; mi < 4; ++mi)
                af[mi] = *(const short8*)(At + (wm + mi * 16 + fm) * 64 + kk * 32 + kg * 8);
#pragma unroll
            for (int ni = 0; ni < 4; ++ni)
                bfr[ni] = *(const short8*)(Bt + (wn + ni * 16 + fm) * 64 + kk * 32 + kg * 8);
#pragma unroll
            for (int mi = 0; mi < 4; ++mi)
#pragma unroll
                for (int ni = 0; ni < 4; ++ni)
                    acc[mi][ni] = __builtin_amdgcn_mfma_f32_16x16x32_bf16(af[mi], bfr[ni], acc[mi][ni], 0, 0, 0);
        }
        __syncthreads();
    }

    int rlim = cnt - m0;
#pragma unroll
    for (int mi = 0; mi < 4; ++mi) {
#pragma unroll
        for (int i = 0; i < 4; ++i) {
            int r = wm + mi * 16 + kg * 4 + i;
            if (r < rlim) {
                float w = wts_s[r];
                float* orow = out + (size_t)(rows_s[r] / 3) * C_ + n0;
#pragma unroll
                for (int ni = 0; ni < 4; ++ni) {
                    int col = wn + ni * 16 + fm;
                    float v = (acc[mi][ni][i] + b2[e * C_ + n0 + col]) * w;
                    atomicAdd(&orow[col], v);
                }
            }
        }
    }
}

extern "C" void kernel_launch(void* const* d_in, const int* in_sizes, int n_in,
                              void* d_out, int out_size, void* d_ws, size_t ws_size,
                              hipStream_t stream) {
    const float* x  = (const float*)d_in[0];
    const float* gW = (const float*)d_in[1];
    const float* gb = (const float*)d_in[2];
    const float* W1 = (const float*)d_in[3];
    const float* b1 = (const float*)d_in[4];
    const float* W2 = (const float*)d_in[5];
    const float* b2 = (const float*)d_in[6];
    float* out    = (float*)d_out;                 // [B, C]
    float* gw_out = out + (size_t)B_ * C_;         // [B, E]

    char* ws = (char*)d_ws;
    size_t off = 0;
    auto alloc = [&](size_t bytes) -> char* {
        char* p = ws + off;
        off = (off + bytes + 255) & ~(size_t)255;
        return p;
    };
    int*            counts  = (int*)alloc(E_ * 4);
    int*            rowlist = (int*)alloc((size_t)E_ * B_ * 4);
    float*          wtslist = (float*)alloc((size_t)E_ * B_ * 4);
    unsigned short* xb      = (unsigned short*)alloc((size_t)B_ * D_ * 2);
    unsigned short* W1b     = (unsigned short*)alloc((size_t)E_ * H_ * D_ * 2);
    unsigned short* W2b     = (unsigned short*)alloc((size_t)E_ * C_ * H_ * 2);
    unsigned short* hbuf    = (unsigned short*)alloc((size_t)3 * B_ * H_ * 2);
    (void)ws_size; (void)in_sizes; (void)n_in; (void)out_size;

    hipMemsetAsync(counts, 0, E_ * 4, stream);
    hipMemsetAsync(out, 0, (size_t)B_ * C_ * 4, stream);

    gate_kernel<<<B_ / 4, 256, 0, stream>>>(x, gW, gb, gw_out, counts, rowlist, wtslist);
    cast_f32_bf16<<<(B_ * D_ / 4) / 256, 256, 0, stream>>>(x, xb, B_ * D_ / 4);
    cast_f32_bf16<<<(E_ * H_ * D_ / 4) / 256, 256, 0, stream>>>(W1, W1b, E_ * H_ * D_ / 4);
    cast_f32_bf16<<<(E_ * C_ * H_ / 4) / 256, 256, 0, stream>>>(W2, W2b, E_ * C_ * H_ / 4);
    gemm1_kernel<<<dim3(H_ / 128, B_ / 128, E_), 256, 0, stream>>>(xb, W1b, b1, counts, rowlist, hbuf);
    gemm2_kernel<<<dim3(C_ / 128, B_ / 128, E_), 256, 0, stream>>>(hbuf, W2b, b2, counts, rowlist, wtslist, out);
}

// Round 2
// 2097.108 us; speedup vs baseline: 1.0670x; 1.0670x over previous
//
#include <hip/hip_runtime.h>
#include <hip/hip_bf16.h>
#include <math.h>

#define B_ 16384
#define D_ 2048
#define H_ 2048
#define E_ 6
#define C_ 1024

typedef __attribute__((ext_vector_type(8))) short short8;
typedef __attribute__((ext_vector_type(4))) float f32x4;

__device__ __forceinline__ unsigned short f2bf(float f) {
    __hip_bfloat16 h = __float2bfloat16(f);
    return *reinterpret_cast<unsigned short*>(&h);
}

__device__ __forceinline__ void async_copy16(const unsigned short* g, unsigned short* l) {
    __builtin_amdgcn_global_load_lds(
        (const __attribute__((address_space(1))) unsigned int*)(g),
        (__attribute__((address_space(3))) unsigned int*)(l), 16, 0, 0);
}

// ---------------- gate: fp64 logits, top-3, softmax, routing lists ----------------
__global__ void gate_kernel(const float* __restrict__ x, const float* __restrict__ gW,
                            const float* __restrict__ gb, float* __restrict__ gw_out,
                            int* __restrict__ counts, int* __restrict__ rowlist,
                            float* __restrict__ wtslist) {
    int wave = threadIdx.x >> 6;
    int lane = threadIdx.x & 63;
    int row  = blockIdx.x * 4 + wave;
    const float* xr = x + (size_t)row * D_;
    double acc[E_] = {0, 0, 0, 0, 0, 0};
    for (int i = 0; i < D_ / 64; ++i) {
        int d = i * 64 + lane;
        double xv = (double)xr[d];
#pragma unroll
        for (int e = 0; e < E_; ++e) acc[e] += xv * (double)gW[e * D_ + d];
    }
#pragma unroll
    for (int off = 32; off > 0; off >>= 1) {
#pragma unroll
        for (int e = 0; e < E_; ++e) acc[e] += __shfl_down(acc[e], off);
    }
    if (lane == 0) {
        double lg[E_];
#pragma unroll
        for (int e = 0; e < E_; ++e) lg[e] = acc[e] + (double)gb[e];
        bool used[E_] = {false, false, false, false, false, false};
        int idx[3]; double val[3];
        for (int k = 0; k < 3; ++k) {
            int best = -1; double bv = -1e300;
            for (int e = 0; e < E_; ++e)
                if (!used[e] && lg[e] > bv) { bv = lg[e]; best = e; }
            used[best] = true; idx[k] = best; val[k] = bv;
        }
        double m = val[0];
        double w[3]; double s = 0.0;
        for (int k = 0; k < 3; ++k) { w[k] = exp(val[k] - m); s += w[k]; }
        float gwv[E_] = {0.f, 0.f, 0.f, 0.f, 0.f, 0.f};
        for (int k = 0; k < 3; ++k) gwv[idx[k]] = (float)(w[k] / s);
#pragma unroll
        for (int e = 0; e < E_; ++e) gw_out[(size_t)row * E_ + e] = gwv[e];
        for (int k = 0; k < 3; ++k) {
            int e = idx[k];
            int pos = atomicAdd(&counts[e], 1);
            rowlist[(size_t)e * B_ + pos] = row * 3 + k;   // global slot id
            wtslist[(size_t)e * B_ + pos] = (float)(w[k] / s);
        }
    }
}

// ---------------- f32 -> bf16 cast (vectorized) ----------------
__global__ void cast_f32_bf16(const float* __restrict__ in, unsigned short* __restrict__ out, int n4) {
    int i = blockIdx.x * blockDim.x + threadIdx.x;
    if (i < n4) {
        float4 v = ((const float4*)in)[i];
        ushort4 u;
        u.x = f2bf(v.x); u.y = f2bf(v.y); u.z = f2bf(v.z); u.w = f2bf(v.w);
        ((ushort4*)out)[i] = u;
    }
}

// ---------------- GEMM1: h[slot, n] = gelu(x[row] @ W1[e]^T + b1[e]) ----------------
// LDS layout: tile row r (128 B) holds its 8 granules (16 B each) XOR-swizzled:
// physical granule p at LDS holds logical granule p ^ (r & 7). This spreads a
// wave's fragment reads (fixed logical granule, 16 rows) over all 32 banks.
__global__ __launch_bounds__(256) void gemm1_kernel(
    const unsigned short* __restrict__ xb, const unsigned short* __restrict__ W1b,
    const float* __restrict__ b1, const int* __restrict__ counts,
    const int* __restrict__ rowlist, unsigned short* __restrict__ hbuf) {
    int e = blockIdx.z;
    int cnt = counts[e];
    int m0 = blockIdx.y * 128;
    if (m0 >= cnt) return;
    int n0 = blockIdx.x * 128;

    __shared__ __align__(16) unsigned short At[128 * 64];
    __shared__ __align__(16) unsigned short Bt[128 * 64];
    int tid = threadIdx.x;
    const int* rlist = rowlist + (size_t)e * B_;

    const unsigned short* aptr[4];
    const unsigned short* bptr[4];
#pragma unroll
    for (int it = 0; it < 4; ++it) {
        int seg = it * 256 + tid;
        int r = seg >> 3, c = seg & 7;
        int cs = c ^ (r & 7);                 // source-side swizzle
        int idx = m0 + r; if (idx >= cnt) idx = cnt - 1;
        aptr[it] = xb + (size_t)(rlist[idx] / 3) * D_ + cs * 8;
        bptr[it] = W1b + (size_t)e * H_ * D_ + (size_t)(n0 + r) * D_ + cs * 8;
    }
    int lane = tid & 63;
    int wv = tid >> 6;
    int wm = (wv & 1) * 64;
    int wn = (wv >> 1) * 64;
    int fm = lane & 15;
    int kg = lane >> 4;
    int fsw = fm & 7;                          // read-side swizzle key
    f32x4 acc[4][4] = {};

    for (int k0 = 0; k0 < D_; k0 += 64) {
#pragma unroll
        for (int it = 0; it < 4; ++it) {
            async_copy16(aptr[it] + k0, At + (it * 256 + tid) * 8);
            async_copy16(bptr[it] + k0, Bt + (it * 256 + tid) * 8);
        }
        __syncthreads();
#pragma unroll
        for (int kk = 0; kk < 2; ++kk) {
            int g = kk * 4 + kg;
            int go = (g ^ fsw) * 8;
            short8 af[4], bfr[4];
#pragma unroll
            for (int mi = 0; mi < 4; ++mi)
                af[mi] = *(const short8*)(At + (wm + mi * 16 + fm) * 64 + go);
#pragma unroll
            for (int ni = 0; ni < 4; ++ni)
                bfr[ni] = *(const short8*)(Bt + (wn + ni * 16 + fm) * 64 + go);
#pragma unroll
            for (int mi = 0; mi < 4; ++mi)
#pragma unroll
                for (int ni = 0; ni < 4; ++ni)
                    acc[mi][ni] = __builtin_amdgcn_mfma_f32_16x16x32_bf16(af[mi], bfr[ni], acc[mi][ni], 0, 0, 0);
        }
        __syncthreads();
    }

    int rlim = cnt - m0;
#pragma unroll
    for (int mi = 0; mi < 4; ++mi) {
#pragma unroll
        for (int i = 0; i < 4; ++i) {
            int r = wm + mi * 16 + kg * 4 + i;
            if (r < rlim) {
                size_t base = (size_t)rlist[m0 + r] * H_ + n0;
#pragma unroll
                for (int ni = 0; ni < 4; ++ni) {
                    int col = wn + ni * 16 + fm;
                    float v = acc[mi][ni][i] + b1[e * H_ + n0 + col];
                    v = 0.5f * v * (1.0f + erff(v * 0.70710678118654752f)); // exact GELU
                    hbuf[base + col] = f2bf(v);
                }
            }
        }
    }
}

// ---------------- GEMM2: out[row] += w * (h[slot] @ W2[e]^T + b2[e]) ----------------
__global__ __launch_bounds__(256) void gemm2_kernel(
    const unsigned short* __restrict__ hbuf, const unsigned short* __restrict__ W2b,
    const float* __restrict__ b2, const int* __restrict__ counts,
    const int* __restrict__ rowlist, const float* __restrict__ wtslist,
    float* __restrict__ out) {
    int e = blockIdx.z;
    int cnt = counts[e];
    int m0 = blockIdx.y * 128;
    if (m0 >= cnt) return;
    int n0 = blockIdx.x * 128;

    __shared__ __align__(16) unsigned short At[128 * 64];
    __shared__ __align__(16) unsigned short Bt[128 * 64];
    int tid = threadIdx.x;
    const int* rlist = rowlist + (size_t)e * B_;
    const float* wlist = wtslist + (size_t)e * B_;

    const unsigned short* aptr[4];
    const unsigned short* bptr[4];
#pragma unroll
    for (int it = 0; it < 4; ++it) {
        int seg = it * 256 + tid;
        int r = seg >> 3, c = seg & 7;
        int cs = c ^ (r & 7);
        int idx = m0 + r; if (idx >= cnt) idx = cnt - 1;
        aptr[it] = hbuf + (size_t)rlist[idx] * H_ + cs * 8;
        bptr[it] = W2b + (size_t)e * C_ * H_ + (size_t)(n0 + r) * H_ + cs * 8;
    }
    int lane = tid & 63;
    int wv = tid >> 6;
    int wm = (wv & 1) * 64;
    int wn = (wv >> 1) * 64;
    int fm = lane & 15;
    int kg = lane >> 4;
    int fsw = fm & 7;
    f32x4 acc[4][4] = {};

    for (int k0 = 0; k0 < H_; k0 += 64) {
#pragma unroll
        for (int it = 0; it < 4; ++it) {
            async_copy16(aptr[it] + k0, At + (it * 256 + tid) * 8);
            async_copy16(bptr[it] + k0, Bt + (it * 256 + tid) * 8);
        }
        __syncthreads();
#pragma unroll
        for (int kk = 0; kk < 2; ++kk) {
            int g = kk * 4 + kg;
            int go = (g ^ fsw) * 8;
            short8 af[4], bfr[4];
#pragma unroll
            for (int mi = 0; mi < 4; ++mi)
                af[mi] = *(const short8*)(At + (wm + mi * 16 + fm) * 64 + go);
#pragma unroll
            for (int ni = 0; ni < 4; ++ni)
                bfr[ni] = *(const short8*)(Bt + (wn + ni * 16 + fm) * 64 + go);
#pragma unroll
            for (int mi = 0; mi < 4; ++mi)
#pragma unroll
                for (int ni = 0; ni < 4; ++ni)
                    acc[mi][ni] = __builtin_amdgcn_mfma_f32_16x16x32_bf16(af[mi], bfr[ni], acc[mi][ni], 0, 0, 0);
        }
        __syncthreads();
    }

    int rlim = cnt - m0;
#pragma unroll
    for (int mi = 0; mi < 4; ++mi) {
#pragma unroll
        for (int i = 0; i < 4; ++i) {
            int r = wm + mi * 16 + kg * 4 + i;
            if (r < rlim) {
                float w = wlist[m0 + r];
                float* orow = out + (size_t)(rlist[m0 + r] / 3) * C_ + n0;
#pragma unroll
                for (int ni = 0; ni < 4; ++ni) {
                    int col = wn + ni * 16 + fm;
                    float v = (acc[mi][ni][i] + b2[e * C_ + n0 + col]) * w;
                    atomicAdd(&orow[col], v);
                }
            }
        }
    }
}

extern "C" void kernel_launch(void* const* d_in, const int* in_sizes, int n_in,
                              void* d_out, int out_size, void* d_ws, size_t ws_size,
                              hipStream_t stream) {
    const float* x  = (const float*)d_in[0];
    const float* gW = (const float*)d_in[1];
    const float* gb = (const float*)d_in[2];
    const float* W1 = (const float*)d_in[3];
    const float* b1 = (const float*)d_in[4];
    const float* W2 = (const float*)d_in[5];
    const float* b2 = (const float*)d_in[6];
    float* out    = (float*)d_out;                 // [B, C]
    float* gw_out = out + (size_t)B_ * C_;         // [B, E]

    char* ws = (char*)d_ws;
    size_t off = 0;
    auto alloc = [&](size_t bytes) -> char* {
        char* p = ws + off;
        off = (off + bytes + 255) & ~(size_t)255;
        return p;
    };
    int*            counts  = (int*)alloc(E_ * 4);
    int*            rowlist = (int*)alloc((size_t)E_ * B_ * 4);
    float*          wtslist = (float*)alloc((size_t)E_ * B_ * 4);
    unsigned short* xb      = (unsigned short*)alloc((size_t)B_ * D_ * 2);
    unsigned short* W1b     = (unsigned short*)alloc((size_t)E_ * H_ * D_ * 2);
    unsigned short* W2b     = (unsigned short*)alloc((size_t)E_ * C_ * H_ * 2);
    unsigned short* hbuf    = (unsigned short*)alloc((size_t)3 * B_ * H_ * 2);
    (void)ws_size; (void)in_sizes; (void)n_in; (void)out_size;

    hipMemsetAsync(counts, 0, E_ * 4, stream);
    hipMemsetAsync(out, 0, (size_t)B_ * C_ * 4, stream);

    gate_kernel<<<B_ / 4, 256, 0, stream>>>(x, gW, gb, gw_out, counts, rowlist, wtslist);
    cast_f32_bf16<<<(B_ * D_ / 4) / 256, 256, 0, stream>>>(x, xb, B_ * D_ / 4);
    cast_f32_bf16<<<(E_ * H_ * D_ / 4) / 256, 256, 0, stream>>>(W1, W1b, E_ * H_ * D_ / 4);
    cast_f32_bf16<<<(E_ * C_ * H_ / 4) / 256, 256, 0, stream>>>(W2, W2b, E_ * C_ * H_ / 4);
    gemm1_kernel<<<dim3(H_ / 128, B_ / 128, E_), 256, 0, stream>>>(xb, W1b, b1, counts, rowlist, hbuf);
    gemm2_kernel<<<dim3(C_ / 128, B_ / 128, E_), 256, 0, stream>>>(hbuf, W2b, b2, counts, rowlist, wtslist, out);
}